// Round 8
// baseline (151.645 us; speedup 1.0000x reference)
//
#include <hip/hip_runtime.h>
#include <math.h>

// Problem constants: V=50000, D=100, B=16, S=128, U=100, L=2
#define NB 16
#define SS 128
#define DD 100
#define KK 100
#define T_TILE 8
#define NTILES 16
#define NT 512          // 8 waves = 4 d-quarters (h) x 2 pos-groups (g)

__device__ __forceinline__ float dot4(const float4 a, const float4 b) {
  return a.x * b.x + a.y * b.y + a.z * b.z + a.w * b.w;
}
// exact x/25 for x < 2560
__device__ __forceinline__ int div25(int x) { return (x * 10486) >> 18; }

// ---------------------------------------------------------------------------
// V staging, reg half (coalesced, linear source). 2500 granules of 16B.
// ---------------------------------------------------------------------------
__device__ __forceinline__ void issue5(const float* __restrict__ gv, int tid,
                                       float4 (&gl)[5]) {
#pragma unroll
  for (int r = 0; r < 5; ++r) {
    const int g = tid + 512 * r;
    if (g < 2500) gl[r] = *(const float4*)(gv + 4 * g);
  }
}
// LDS half: chunk (k, su) -> f4 idx su*100 + (k&1)*50 + ((k>>1)+su)%50.
// Write quads ~(5su)%8, read quads consecutive -> both sides conflict-free.
__device__ __forceinline__ void write5(float* __restrict__ vbuf, int tid,
                                       const float4 (&gl)[5]) {
#pragma unroll
  for (int r = 0; r < 5; ++r) {
    const int g = tid + 512 * r;
    if (g < 2500) {
      const int k = div25(g), su = g - 25 * k;
      int col = (k >> 1) + su; if (col >= 50) col -= 50;
      ((float4*)vbuf)[su * 100 + (k & 1) * 50 + col] = gl[r];
    }
  }
}

// ---------------------------------------------------------------------------
// One projection stage. MODE 0: complex x; MODE 1: real x.
// CM 1: m = |Y|^2*iv ; CM 2: m = |w0 Y(p)+w1 Y(p+1)|^2*iv ; CM 3: y3 = Y raw.
// Lane owns k-pair (2kp, 2kp+1); wave (h,g): d-chunks [O,O+nu), positions 6g+e.
// On entry glr holds part-r global data; on exit it holds gnext's part-r data.
// ---------------------------------------------------------------------------
template<int MODE, int CM>
__device__ __forceinline__ void do_stage(
    const float* __restrict__ gvr, const float* __restrict__ gvi,
    const float* __restrict__ gnext,
    float* __restrict__ vbuf, float4 (&glr)[5],
    const float* __restrict__ xR, const float* __restrict__ xI,
    float* __restrict__ outp, float* __restrict__ invvnU,
    const float* __restrict__ es, const float* __restrict__ sc,
    int O, int nu, int pmaxF, int pmaxC,
    int tid, int h, int g, int kp, bool act, int t0)
{
  float4* partlp = (float4*)vbuf;                     // [4][11][50] f4 overlay
  float2* nrmhp  = (float2*)(vbuf + 8800);            // [4][50]
  float4 Vr0[7], Vr1[7], Vi0[7], Vi1[7];
  float n0 = 0.f, n1 = 0.f;

  // 1. part r regs -> LDS
  write5(vbuf, tid, glr);
  __syncthreads();
  // 2. reg-fill r; issue part-i global loads (hide under fill + barrier)
  issue5(gvi, tid, glr);
#pragma unroll
  for (int U = 0; U < 7; ++U) if (U < nu) {
    const int su = O + U;
    int col = kp + su; if (col >= 50) col -= 50;
    const float4* vb4 = (const float4*)vbuf + su * 100 + col;
    Vr0[U] = vb4[0];
    Vr1[U] = vb4[50];
    n0 += dot4(Vr0[U], Vr0[U]);
    n1 += dot4(Vr1[U], Vr1[U]);
  }
  __syncthreads();
  // 3. part i regs -> LDS
  write5(vbuf, tid, glr);
  __syncthreads();
  // 4. reg-fill i; issue next stage's part-r loads
  if (gnext) issue5(gnext, tid, glr);
#pragma unroll
  for (int U = 0; U < 7; ++U) if (U < nu) {
    const int su = O + U;
    int col = kp + su; if (col >= 50) col -= 50;
    const float4* vb4 = (const float4*)vbuf + su * 100 + col;
    Vi0[U] = vb4[0];
    Vi1[U] = vb4[50];
    n0 += dot4(Vi0[U], Vi0[U]);
    n1 += dot4(Vi1[U], Vi1[U]);
  }
  // 5. FMA: x uniform-broadcast from LDS, V in regs
  float ar[6][2] = {{0}}, ai[6][2] = {{0}};
#pragma unroll
  for (int U = 0; U < 7; ++U) if (U < nu) {
    const int du = 4 * (O + U);
#pragma unroll
    for (int e = 0; e < 6; ++e) {
      const int p = 6 * g + e;
      if (p <= pmaxF) {
        const float4 xr = *(const float4*)(xR + p * DD + du);
        if (MODE == 0) {
          const float4 xi = *(const float4*)(xI + p * DD + du);
          ar[e][0] += dot4(Vr0[U], xr) + dot4(Vi0[U], xi);
          ai[e][0] += dot4(Vr0[U], xi) - dot4(Vi0[U], xr);
          ar[e][1] += dot4(Vr1[U], xr) + dot4(Vi1[U], xi);
          ai[e][1] += dot4(Vr1[U], xi) - dot4(Vi1[U], xr);
        } else {
          ar[e][0] += dot4(Vr0[U], xr);
          ai[e][0] += dot4(Vi0[U], xr);
          ar[e][1] += dot4(Vr1[U], xr);
          ai[e][1] += dot4(Vi1[U], xr);
        }
      }
    }
  }
  // 6. partials -> vbuf overlay (V data now dead in LDS)
  if (act) {
#pragma unroll
    for (int e = 0; e < 6; ++e) {
      const int p = 6 * g + e;
      if (p <= pmaxF)
        partlp[(h * 11 + p) * 50 + kp] =
            make_float4(ar[e][0], ai[e][0], ar[e][1], ai[e][1]);
    }
    if (g == 0) nrmhp[h * 50 + kp] = make_float2(n0, n1);
  }
  __syncthreads();
  // 7. combine (h==0 waves; g splits p)
  if (h == 0 && act) {
    const float2 q0 = nrmhp[kp], q1 = nrmhp[50 + kp],
                 q2 = nrmhp[100 + kp], q3 = nrmhp[150 + kp];
    const float iv0 = 1.f / (q0.x + q1.x + q2.x + q3.x);
    const float iv1 = 1.f / (q0.y + q1.y + q2.y + q3.y);
#pragma unroll
    for (int e = 0; e < 6; ++e) {
      const int p = 6 * g + e;
      if (p <= pmaxC) {
        float4 s = partlp[p * 50 + kp];
        {
          const float4 b1 = partlp[(11 + p) * 50 + kp];
          const float4 b2 = partlp[(22 + p) * 50 + kp];
          const float4 b3 = partlp[(33 + p) * 50 + kp];
          s.x += b1.x + b2.x + b3.x;  s.y += b1.y + b2.y + b3.y;
          s.z += b1.z + b2.z + b3.z;  s.w += b1.w + b2.w + b3.w;
        }
        if (CM == 1) {
          *(float2*)(outp + p * DD + 2 * kp) =
              make_float2((s.x * s.x + s.y * s.y) * iv0,
                          (s.z * s.z + s.w * s.w) * iv1);
        } else if (CM == 2) {
          float4 u = partlp[(p + 1) * 50 + kp];
          const float4 c1 = partlp[(12 + p) * 50 + kp];
          const float4 c2 = partlp[(23 + p) * 50 + kp];
          const float4 c3 = partlp[(34 + p) * 50 + kp];
          u.x += c1.x + c2.x + c3.x;  u.y += c1.y + c2.y + c3.y;
          u.z += c1.z + c2.z + c3.z;  u.w += c1.w + c2.w + c3.w;
          const int t = t0 + p;
          const float w0 = es[t] / sc[0];
          const float w1 = es[t + 1] / sc[1];      // es zero-padded past SS
          const float r0 = w0 * s.x + w1 * u.x, i0 = w0 * s.y + w1 * u.y;
          const float r1 = w0 * s.z + w1 * u.z, i1 = w0 * s.w + w1 * u.w;
          *(float2*)(outp + p * DD + 2 * kp) =
              make_float2((r0 * r0 + i0 * i0) * iv0, (r1 * r1 + i1 * i1) * iv1);
        } else {
          *(float4*)(outp + p * 2 * DD + 4 * kp) = s;   // y3: [p][k] float2
        }
      }
    }
    if (CM == 3 && g == 0) { invvnU[2 * kp] = iv0; invvnU[2 * kp + 1] = iv1; }
  }
  __syncthreads();
}

// ---------------------------------------------------------------------------
__global__ __launch_bounds__(NT) void k_fused(
    const int* __restrict__ seq,
    const float* __restrict__ ampT, const float* __restrict__ phT,
    const float* __restrict__ pkr, const float* __restrict__ pki,
    const float* __restrict__ mkr, const float* __restrict__ mki,
    float* __restrict__ partg)
{
  __shared__ __align__(16) float vbuf[10000];   // 40 KB: V part / partl+nrmh
  __shared__ __align__(16) float xb[2208];      // phi_r|phi_i -> m1|m2 -> y3
  __shared__ float es[SS + 8], wnl[SS], invvnU[KK], sc[3], redw[2];

  const int tid  = threadIdx.x;
  const int lane = tid & 63;
  const int wid  = tid >> 6;
  const int h    = wid & 3;
  const int g    = wid >> 2;
  const bool act = lane < 50;
  const int kp   = act ? lane : 49;
  const int bt   = blockIdx.x;
  const int b    = bt >> 4;
  const int t0   = (bt & 15) * T_TILE;
  const int sb   = b * SS;
  const int O    = (h == 0) ? 0 : 1 + 6 * h;    // 0,7,13,19
  const int nu   = (h == 0) ? 7 : 6;

  float4 glr[5];
  issue5(pkr, tid, glr);                        // stage-1 part r, issued first

  // --- prologue A: ||amp|| + exp for all 128 positions of batch b ---
  {
    const int t = tid >> 2, qq = tid & 3;
    const int row = seq[sb + t];
    const float* ap = ampT + (long)row * DD;
    float s = 0.f;
#pragma unroll
    for (int i = 0; i < 7; ++i) {
      const int j = qq + 4 * i;
      if (j < 25) {
        const float4 a4 = *(const float4*)(ap + 4 * j);
        s += dot4(a4, a4);
      }
    }
    s += __shfl_xor(s, 1);
    s += __shfl_xor(s, 2);
    if (qq == 0) { const float n = sqrtf(s); wnl[t] = n; es[t] = expf(n); }
  }
  if (tid >= 512 - 8) es[SS + tid - (512 - 8)] = 0.f;   // pad es[128..135]
  __syncthreads();

  // --- prologue B: E-reduce + phi for the 11-position halo ---
  if (tid < SS) {
    float v = es[tid];
#pragma unroll
    for (int m = 32; m; m >>= 1) v += __shfl_xor(v, m);
    if ((tid & 63) == 0) redw[tid >> 6] = v;
  }
  for (int e2 = tid; e2 < 11 * DD; e2 += NT) {
    const int p = e2 / DD, d = e2 - p * DD;
    const int t = t0 + p;
    float pr = 0.f, pi = 0.f;
    if (t < SS) {
      const int row = seq[sb + t];
      const float a  = ampT[(long)row * DD + d];
      const float ph = phT[(long)row * DD + d];
      float sv, cv; sincosf(ph, &sv, &cv);
      const float an = a / wnl[t];
      pr = an * cv; pi = an * sv;
    }
    xb[p * DD + d]        = pr;
    xb[1100 + p * DD + d] = pi;
  }
  __syncthreads();
  if (tid == 0) {
    const float E = redw[0] + redw[1];
    sc[0] = E; sc[1] = E - es[0] + 1.f; sc[2] = E - es[0] - es[1] + 2.f;
  }
  // (sc consumed first at stage-2 combine, many barriers later)

  // --- stage 1: m1 = |<v0, phi>|^2 * iv   -> xb[0..1100) ---
  do_stage<0, 1>(pkr, pki, pkr + DD * DD, vbuf, glr, xb, xb + 1100,
                 xb, invvnU, es, sc, O, nu, 10, 10, tid, h, g, kp, act, t0);
  // --- stage 2: m2 = |2-tap <v1, m1>|^2 * iv -> xb[1100..2200) ---
  do_stage<1, 2>(pkr + DD * DD, pki + DD * DD, mkr, vbuf, glr, xb, xb,
                 xb + 1100, invvnU, es, sc, O, nu, 10, 9, tid, h, g, kp, act, t0);
  // --- stage 3: y3 = <u, m2> raw -> xb[0..2000) as [10][100] float2 ---
  do_stage<1, 3>(mkr, mki, nullptr, vbuf, glr, xb + 1100, xb + 1100,
                 xb, invvnU, es, sc, O, nu, 9, 9, tid, h, g, kp, act, t0);

  // --- final: 3-tap window, |.|^2, * wn[t] * invvnU; sum over tile ---
  if (tid < KK) {
    const float2* y3f = (const float2*)xb;
    const int k = tid;
    const float iE = 1.f / sc[0], iZ1 = 1.f / sc[1], iZ2 = 1.f / sc[2];
    float acc = 0.f;
#pragma unroll
    for (int p = 0; p < T_TILE; ++p) {
      const int t = t0 + p;
      const float w0 = es[t] * iE;
      const float w1 = es[t + 1] * iZ1;
      const float w2 = es[t + 2] * iZ2;
      const float2 a = y3f[p * DD + k], bb = y3f[(p + 1) * DD + k],
                   c = y3f[(p + 2) * DD + k];
      const float qr = w0 * a.x + w1 * bb.x + w2 * c.x;
      const float qi = w0 * a.y + w1 * bb.y + w2 * c.y;
      acc += wnl[t] * (qr * qr + qi * qi);
    }
    partg[bt * KK + k] = acc * invvnU[k];
  }
}

// ---------------------------------------------------------------------------
__global__ __launch_bounds__(128) void k_out(
    const float* __restrict__ partg, const float* __restrict__ dw,
    const float* __restrict__ db, float* __restrict__ out)
{
  __shared__ float pr[KK];
  const int b = blockIdx.x, tid = threadIdx.x;
  if (tid < KK) {
    float s = 0.f;
#pragma unroll
    for (int q = 0; q < NTILES; ++q) s += partg[(b * NTILES + q) * KK + tid];
    pr[tid] = s;
  }
  __syncthreads();
  if (tid < 2) {
    float s = db[tid];
    for (int k = 0; k < KK; ++k) s += pr[k] * dw[k * 2 + tid];
    out[b * 2 + tid] = s;
  }
}

// ---------------------------------------------------------------------------
extern "C" void kernel_launch(void* const* d_in, const int* in_sizes, int n_in,
                              void* d_out, int out_size, void* d_ws, size_t ws_size,
                              hipStream_t stream) {
  const int*   seq  = (const int*)d_in[0];
  const float* ampT = (const float*)d_in[1];
  const float* phT  = (const float*)d_in[2];
  const float* pkr  = (const float*)d_in[3];
  const float* pki  = (const float*)d_in[4];
  const float* mkr  = (const float*)d_in[5];
  const float* mki  = (const float*)d_in[6];
  const float* dw   = (const float*)d_in[7];
  const float* db   = (const float*)d_in[8];
  float* out   = (float*)d_out;
  float* partg = (float*)d_ws;   // [256][100] floats

  k_fused<<<NB * NTILES, NT, 0, stream>>>(seq, ampT, phT, pkr, pki, mkr, mki, partg);
  k_out  <<<NB,          128, 0, stream>>>(partg, dw, db, out);
}